// Round 3
// baseline (550.472 us; speedup 1.0000x reference)
//
#include <hip/hip_runtime.h>

typedef __bf16 bf16;
typedef bf16 bf16x4 __attribute__((ext_vector_type(4)));
typedef bf16 bf16x8 __attribute__((ext_vector_type(8)));
typedef float floatx4 __attribute__((ext_vector_type(4)));

#define LDT 72   // 64-col bf16 tile stride (144 B): 2-way bank alias only (free)
#define LDT2 40  // 32-col bf16 tile stride (80 B)

// Wqkv [768,2304] fp32 -> WqkvT [2304,768] fp32
__global__ __launch_bounds__(256) void transpose_f32(const float* __restrict__ in,
                                                     float* __restrict__ out,
                                                     int K, int N) {
  int k = blockIdx.x * 256 + threadIdx.x;
  int n = blockIdx.y;
  if (k < K) out[(size_t)n * K + k] = in[(size_t)k * N + n];
}

// Wproj [768,768] fp32 -> WprojT [768,768] bf16
__global__ __launch_bounds__(256) void transpose_f32_bf16(const float* __restrict__ in,
                                                          bf16* __restrict__ out,
                                                          int K, int N) {
  int k = blockIdx.x * 256 + threadIdx.x;
  int n = blockIdx.y;
  if (k < K) out[(size_t)n * K + k] = (bf16)in[(size_t)k * N + n];
}

// qkv = x @ WqkvT^T with bf16 hi/lo split (3-term MFMA, ~fp32 precision).
// cols [0,1536) -> qk32 fp32; cols [1536,2304) -> v16 bf16.
__global__ __launch_bounds__(256) void gemm1_split(const float* __restrict__ A,
                                                   const float* __restrict__ Bt,
                                                   float* __restrict__ qk32,
                                                   bf16* __restrict__ v16,
                                                   int M, int N, int K) {
  __shared__ bf16 Ah[128 * LDT2], Al[128 * LDT2];
  __shared__ bf16 Bh[128 * LDT2], Bl[128 * LDT2];
  int tid = threadIdx.x;
  int lane = tid & 63, wid = tid >> 6;
  int quad = lane >> 4, l16 = lane & 15;
  int wy = wid >> 1, wx = wid & 1;
  int m0 = blockIdx.x * 128, n0 = blockIdx.y * 128;
  int srow = tid >> 3, scol4 = (tid & 7) * 4;
  floatx4 acc[4][4] = {};
  for (int k0 = 0; k0 < K; k0 += 32) {
    for (int p = 0; p < 4; ++p) {
      int r = srow + p * 32;
      float4 av = *(const float4*)(A + (size_t)(m0 + r) * K + k0 + scol4);
      float4 bv = *(const float4*)(Bt + (size_t)(n0 + r) * K + k0 + scol4);
      float aa[4] = {av.x, av.y, av.z, av.w};
      float bb[4] = {bv.x, bv.y, bv.z, bv.w};
      bf16x4 ah, al, bh, bl;
      for (int e = 0; e < 4; ++e) {
        bf16 h = (bf16)aa[e]; ah[e] = h; al[e] = (bf16)(aa[e] - (float)h);
        h = (bf16)bb[e]; bh[e] = h; bl[e] = (bf16)(bb[e] - (float)h);
      }
      *(bf16x4*)(Ah + r * LDT2 + scol4) = ah;
      *(bf16x4*)(Al + r * LDT2 + scol4) = al;
      *(bf16x4*)(Bh + r * LDT2 + scol4) = bh;
      *(bf16x4*)(Bl + r * LDT2 + scol4) = bl;
    }
    __syncthreads();
    bf16x8 afh[4], afl[4], bfh[4], bfl[4];
    for (int i = 0; i < 4; ++i) {
      afh[i] = *(const bf16x8*)(Ah + (wy * 64 + i * 16 + l16) * LDT2 + quad * 8);
      afl[i] = *(const bf16x8*)(Al + (wy * 64 + i * 16 + l16) * LDT2 + quad * 8);
    }
    for (int j = 0; j < 4; ++j) {
      bfh[j] = *(const bf16x8*)(Bh + (wx * 64 + j * 16 + l16) * LDT2 + quad * 8);
      bfl[j] = *(const bf16x8*)(Bl + (wx * 64 + j * 16 + l16) * LDT2 + quad * 8);
    }
    for (int i = 0; i < 4; ++i)
      for (int j = 0; j < 4; ++j) {
        acc[i][j] = __builtin_amdgcn_mfma_f32_16x16x32_bf16(afl[i], bfh[j], acc[i][j], 0, 0, 0);
        acc[i][j] = __builtin_amdgcn_mfma_f32_16x16x32_bf16(afh[i], bfl[j], acc[i][j], 0, 0, 0);
        acc[i][j] = __builtin_amdgcn_mfma_f32_16x16x32_bf16(afh[i], bfh[j], acc[i][j], 0, 0, 0);
      }
    __syncthreads();
  }
  for (int i = 0; i < 4; ++i) {
    int row = m0 + wy * 64 + i * 16 + quad * 4;
    for (int j = 0; j < 4; ++j) {
      int col = n0 + wx * 64 + j * 16 + l16;
      for (int r = 0; r < 4; ++r) {
        if (n0 < 1536) qk32[(size_t)(row + r) * 1536 + col] = acc[i][j][r];
        else           v16[(size_t)(row + r) * 768 + (col - 1536)] = (bf16)acc[i][j][r];
      }
    }
  }
}

// C[M,N] = A[M,K](bf16) * Bt[N,K]^T(bf16), fp32 out. M%128==0, N%128==0, K%64==0.
__global__ __launch_bounds__(256) void gemm_bt_f32(const bf16* __restrict__ A,
                                                   const bf16* __restrict__ Bt,
                                                   float* __restrict__ C,
                                                   int M, int N, int K) {
  __shared__ bf16 As[128 * LDT];
  __shared__ bf16 Bs[128 * LDT];
  int tid = threadIdx.x;
  int lane = tid & 63, wid = tid >> 6;
  int quad = lane >> 4, l16 = lane & 15;
  int wy = wid >> 1, wx = wid & 1;
  int m0 = blockIdx.x * 128, n0 = blockIdx.y * 128;
  int srow = tid >> 3, scol = (tid & 7) * 8;
  floatx4 acc[4][4] = {};
  for (int k0 = 0; k0 < K; k0 += 64) {
    for (int p = 0; p < 4; ++p) {
      int r = srow + p * 32;
      *(uint4*)(As + r * LDT + scol) = *(const uint4*)(A + (size_t)(m0 + r) * K + k0 + scol);
      *(uint4*)(Bs + r * LDT + scol) = *(const uint4*)(Bt + (size_t)(n0 + r) * K + k0 + scol);
    }
    __syncthreads();
    for (int kk = 0; kk < 64; kk += 32) {
      bf16x8 af[4], bfr[4];
      for (int i = 0; i < 4; ++i)
        af[i] = *(const bf16x8*)(As + (wy * 64 + i * 16 + l16) * LDT + kk + quad * 8);
      for (int j = 0; j < 4; ++j)
        bfr[j] = *(const bf16x8*)(Bs + (wx * 64 + j * 16 + l16) * LDT + kk + quad * 8);
      for (int i = 0; i < 4; ++i)
        for (int j = 0; j < 4; ++j)
          acc[i][j] = __builtin_amdgcn_mfma_f32_16x16x32_bf16(af[i], bfr[j], acc[i][j], 0, 0, 0);
    }
    __syncthreads();
  }
  for (int i = 0; i < 4; ++i) {
    int row = m0 + wy * 64 + i * 16 + quad * 4;
    for (int j = 0; j < 4; ++j) {
      int col = n0 + wx * 64 + j * 16 + l16;
      for (int r = 0; r < 4; ++r)
        C[(size_t)(row + r) * N + col] = acc[i][j][r];
    }
  }
}

// Flash attention. qk32 [B,T,1536] fp32 (q|k per token), v16 [B,T,768] bf16,
// y [B,T,768] bf16. One block per (b,h,64-row Q tile); QK^T via hi/lo split MFMA.
__global__ __launch_bounds__(256) void flash_attn(const float* __restrict__ qk32,
                                                  const bf16* __restrict__ v16,
                                                  bf16* __restrict__ y) {
  __shared__ bf16 Qh[64 * LDT], Ql[64 * LDT];
  __shared__ bf16 Kh[64 * LDT], Kl[64 * LDT];
  __shared__ bf16 Vt[64 * LDT];  // V transposed: Vt[d][s]
  __shared__ bf16 Ps[64 * LDT];  // per-wave strips for C->A layout round trip
  const int T = 2048;
  int blk = blockIdx.x;
  int qt = blk & 31;  // 32 q-tiles
  int bh = blk >> 5;
  int b = bh / 12, h = bh - b * 12;
  int tid = threadIdx.x;
  int lane = tid & 63, wid = tid >> 6;
  int quad = lane >> 4, l16 = lane & 15;
  int srow4 = tid >> 4, scol4 = (tid & 15) * 4;
  int srow8 = tid >> 3, scol8 = (tid & 7) * 8;
  size_t qbase = (size_t)b * T * 1536;
  size_t vbase = (size_t)b * T * 768;
  int hoff = h * 64;

  for (int p = 0; p < 4; ++p) {
    int r = srow4 + p * 16;
    float4 qv = *(const float4*)(qk32 + qbase + (size_t)(qt * 64 + r) * 1536 + hoff + scol4);
    float aa[4] = {qv.x, qv.y, qv.z, qv.w};
    bf16x4 hv, lv;
    for (int e = 0; e < 4; ++e) {
      bf16 hh = (bf16)aa[e]; hv[e] = hh; lv[e] = (bf16)(aa[e] - (float)hh);
    }
    *(bf16x4*)(Qh + r * LDT + scol4) = hv;
    *(bf16x4*)(Ql + r * LDT + scol4) = lv;
  }
  __syncthreads();
  bf16x8 qfh[2], qfl[2];
  for (int kk = 0; kk < 2; ++kk) {
    qfh[kk] = *(const bf16x8*)(Qh + (wid * 16 + l16) * LDT + kk * 32 + quad * 8);
    qfl[kk] = *(const bf16x8*)(Ql + (wid * 16 + l16) * LDT + kk * 32 + quad * 8);
  }

  float m_i[4] = {-1e30f, -1e30f, -1e30f, -1e30f};
  float l_i[4] = {0.f, 0.f, 0.f, 0.f};
  floatx4 o[4] = {};

  for (int kt = 0; kt < 32; ++kt) {
    __syncthreads();  // protect restage vs previous iteration's reads
    for (int p = 0; p < 4; ++p) {
      int r = srow4 + p * 16;
      float4 kv = *(const float4*)(qk32 + qbase + (size_t)(kt * 64 + r) * 1536 + 768 + hoff + scol4);
      float aa[4] = {kv.x, kv.y, kv.z, kv.w};
      bf16x4 hv, lv;
      for (int e = 0; e < 4; ++e) {
        bf16 hh = (bf16)aa[e]; hv[e] = hh; lv[e] = (bf16)(aa[e] - (float)hh);
      }
      *(bf16x4*)(Kh + r * LDT + scol4) = hv;
      *(bf16x4*)(Kl + r * LDT + scol4) = lv;
    }
    for (int p = 0; p < 2; ++p) {
      int r = srow8 + p * 32;
      union { uint4 u; bf16 e[8]; } vv;
      vv.u = *(const uint4*)(v16 + vbase + (size_t)(kt * 64 + r) * 768 + hoff + scol8);
      for (int e = 0; e < 8; ++e) Vt[(scol8 + e) * LDT + r] = vv.e[e];
    }
    __syncthreads();

    // S = Q K^T (hi/lo split), scaled by sqrt(Dh)=8 per reference
    floatx4 sf[4];
    const floatx4 z4 = {0.f, 0.f, 0.f, 0.f};
    for (int j = 0; j < 4; ++j) sf[j] = z4;
    for (int kk = 0; kk < 2; ++kk)
      for (int j = 0; j < 4; ++j) {
        bf16x8 kh = *(const bf16x8*)(Kh + (j * 16 + l16) * LDT + kk * 32 + quad * 8);
        bf16x8 kl = *(const bf16x8*)(Kl + (j * 16 + l16) * LDT + kk * 32 + quad * 8);
        sf[j] = __builtin_amdgcn_mfma_f32_16x16x32_bf16(qfl[kk], kh, sf[j], 0, 0, 0);
        sf[j] = __builtin_amdgcn_mfma_f32_16x16x32_bf16(qfh[kk], kl, sf[j], 0, 0, 0);
        sf[j] = __builtin_amdgcn_mfma_f32_16x16x32_bf16(qfh[kk], kh, sf[j], 0, 0, 0);
      }
    for (int j = 0; j < 4; ++j) sf[j] *= 8.0f;

    // online softmax; lane holds rows quad*4+r (col l16) of its wave's strip
    for (int r = 0; r < 4; ++r) {
      float mx = fmaxf(fmaxf(sf[0][r], sf[1][r]), fmaxf(sf[2][r], sf[3][r]));
      for (int off = 1; off < 16; off <<= 1) mx = fmaxf(mx, __shfl_xor(mx, off));
      float m_new = fmaxf(m_i[r], mx);
      float alpha = __expf(m_i[r] - m_new);
      float rowsum = 0.f;
      for (int j = 0; j < 4; ++j) {
        float pv = __expf(sf[j][r] - m_new);
        sf[j][r] = pv;
        rowsum += pv;
      }
      for (int off = 1; off < 16; off <<= 1) rowsum += __shfl_xor(rowsum, off);
      l_i[r] = l_i[r] * alpha + rowsum;
      m_i[r] = m_new;
      for (int dn = 0; dn < 4; ++dn) o[dn][r] *= alpha;
    }

    // P: C-layout -> LDS -> A-layout (wave-private strip)
    for (int j = 0; j < 4; ++j)
      for (int r = 0; r < 4; ++r)
        Ps[(wid * 16 + quad * 4 + r) * LDT + j * 16 + l16] = (bf16)sf[j][r];
    for (int kk = 0; kk < 2; ++kk) {
      bf16x8 pf = *(const bf16x8*)(Ps + (wid * 16 + l16) * LDT + kk * 32 + quad * 8);
      for (int dn = 0; dn < 4; ++dn) {
        bf16x8 vf = *(const bf16x8*)(Vt + (dn * 16 + l16) * LDT + kk * 32 + quad * 8);
        o[dn] = __builtin_amdgcn_mfma_f32_16x16x32_bf16(pf, vf, o[dn], 0, 0, 0);
      }
    }
  }

  for (int r = 0; r < 4; ++r) {
    float invl = 1.0f / l_i[r];
    int t = qt * 64 + wid * 16 + quad * 4 + r;
    size_t off = ((size_t)(b * T + t)) * 768 + hoff;
    for (int dn = 0; dn < 4; ++dn)
      y[off + dn * 16 + l16] = (bf16)(o[dn][r] * invl);
  }
}

extern "C" void kernel_launch(void* const* d_in, const int* in_sizes, int n_in,
                              void* d_out, int out_size, void* d_ws, size_t ws_size,
                              hipStream_t stream) {
  const float* x     = (const float*)d_in[0];  // [4,2048,768] fp32
  const float* Wqkv  = (const float*)d_in[1];  // [768,2304] fp32
  const float* Wproj = (const float*)d_in[2];  // [768,768] fp32
  float* out = (float*)d_out;                  // [4,2048,768] fp32
  char* ws = (char*)d_ws;
  float* qk32   = (float*)ws;               // 8192*1536*4 = 50,331,648 B
  bf16*  v16    = (bf16*)(ws + 50331648);   // 8192*768*2  = 12,582,912 B
  bf16*  y16    = (bf16*)(ws + 62914560);   // 8192*768*2  = 12,582,912 B
  float* WqkvT  = (float*)(ws + 75497472);  // 2304*768*4  =  7,077,888 B
  bf16*  WprojT = (bf16*)(ws + 82575360);   //  768*768*2  =  1,179,648 B
                                            // total 83,755,008 B

  transpose_f32<<<dim3(3, 2304), 256, 0, stream>>>(Wqkv, WqkvT, 768, 2304);
  transpose_f32_bf16<<<dim3(3, 768), 256, 0, stream>>>(Wproj, WprojT, 768, 768);
  gemm1_split<<<dim3(64, 18), 256, 0, stream>>>(x, WqkvT, qk32, v16, 8192, 2304, 768);
  flash_attn<<<1536, 256, 0, stream>>>(qk32, v16, y16);
  gemm_bt_f32<<<dim3(64, 6), 256, 0, stream>>>(y16, WprojT, out, 8192, 768, 768);
}

// Round 5
// 489.011 us; speedup vs baseline: 1.1257x; 1.1257x over previous
//
#include <hip/hip_runtime.h>

typedef __bf16 bf16;
typedef bf16 bf16x4 __attribute__((ext_vector_type(4)));
typedef bf16 bf16x8 __attribute__((ext_vector_type(8)));
typedef float floatx4 __attribute__((ext_vector_type(4)));

#define LDT 72   // 64-col bf16 tile stride: 2-way bank alias only (free per m136)
#define LDT2 40  // 32-col bf16 tile stride

// Wqkv [K=768][N=2304] fp32 -> WqkvT hi/lo [2304][768] bf16 (transpose + split once)
__global__ __launch_bounds__(256) void transpose_split_w(const float* __restrict__ in,
                                                         bf16* __restrict__ outh,
                                                         bf16* __restrict__ outl,
                                                         int K, int N) {
  int k = blockIdx.x * 256 + threadIdx.x;
  int n = blockIdx.y;
  if (k < K) {
    float v = in[(size_t)k * N + n];
    bf16 h = (bf16)v;
    outh[(size_t)n * K + k] = h;
    outl[(size_t)n * K + k] = (bf16)(v - (float)h);
  }
}

// Wproj [768][768] fp32 -> WprojT [768][768] bf16
__global__ __launch_bounds__(256) void transpose_f32_bf16(const float* __restrict__ in,
                                                          bf16* __restrict__ out,
                                                          int K, int N) {
  int k = blockIdx.x * 256 + threadIdx.x;
  int n = blockIdx.y;
  if (k < K) out[(size_t)n * K + k] = (bf16)in[(size_t)k * N + n];
}

// qkv = x @ W^T with 3-term hi/lo MFMA (~fp32 score precision).
// Epilogue writes per-head layouts consumed by flash_attn:
//   cols [0,768):     qh/ql [bh][t][64] bf16 hi/lo
//   cols [768,1536):  kh/kl [bh][t][64] bf16 hi/lo
//   cols [1536,2304): vT    [bh][64][2048] bf16 (pre-transposed)
__global__ __launch_bounds__(256) void gemm1_split(const float* __restrict__ A,
                                                   const bf16* __restrict__ Bth,
                                                   const bf16* __restrict__ Btl,
                                                   bf16* __restrict__ qh, bf16* __restrict__ ql,
                                                   bf16* __restrict__ kh, bf16* __restrict__ kl,
                                                   bf16* __restrict__ vt) {
  __shared__ bf16 Ah[128 * LDT2], Al[128 * LDT2];
  __shared__ bf16 Bh[128 * LDT2], Bl[128 * LDT2];
  int tid = threadIdx.x;
  int lane = tid & 63, wid = tid >> 6;
  int quad = lane >> 4, l16 = lane & 15;
  int wy = wid >> 1, wx = wid & 1;
  int m0 = blockIdx.x * 128, n0 = blockIdx.y * 128;
  int sr = tid >> 2, sc = (tid & 3) * 8;  // 64 rows x 32 cols per pass, 2 passes
  floatx4 acc[4][4] = {};
  for (int k0 = 0; k0 < 768; k0 += 32) {
    for (int p = 0; p < 2; ++p) {  // A: 128x32 fp32, split to hi/lo bf16
      int r = sr + p * 64;
      const float* src = A + (size_t)(m0 + r) * 768 + k0 + sc;
      float4 v0 = *(const float4*)(src);
      float4 v1 = *(const float4*)(src + 4);
      float aa[8] = {v0.x, v0.y, v0.z, v0.w, v1.x, v1.y, v1.z, v1.w};
      bf16x8 hv, lv;
      for (int e = 0; e < 8; ++e) {
        bf16 h = (bf16)aa[e];
        hv[e] = h;
        lv[e] = (bf16)(aa[e] - (float)h);
      }
      *(bf16x8*)(Ah + r * LDT2 + sc) = hv;
      *(bf16x8*)(Al + r * LDT2 + sc) = lv;
    }
    for (int p = 0; p < 2; ++p) {  // B: pre-split bf16, straight 16B copies
      int r = sr + p * 64;
      *(uint4*)(Bh + r * LDT2 + sc) = *(const uint4*)(Bth + (size_t)(n0 + r) * 768 + k0 + sc);
      *(uint4*)(Bl + r * LDT2 + sc) = *(const uint4*)(Btl + (size_t)(n0 + r) * 768 + k0 + sc);
    }
    __syncthreads();
    bf16x8 afh[4], afl[4], bfh[4], bfl[4];
    for (int i = 0; i < 4; ++i) {
      afh[i] = *(const bf16x8*)(Ah + (wy * 64 + i * 16 + l16) * LDT2 + quad * 8);
      afl[i] = *(const bf16x8*)(Al + (wy * 64 + i * 16 + l16) * LDT2 + quad * 8);
    }
    for (int j = 0; j < 4; ++j) {
      bfh[j] = *(const bf16x8*)(Bh + (wx * 64 + j * 16 + l16) * LDT2 + quad * 8);
      bfl[j] = *(const bf16x8*)(Bl + (wx * 64 + j * 16 + l16) * LDT2 + quad * 8);
    }
    for (int i = 0; i < 4; ++i)
      for (int j = 0; j < 4; ++j) {
        acc[i][j] = __builtin_amdgcn_mfma_f32_16x16x32_bf16(afl[i], bfh[j], acc[i][j], 0, 0, 0);
        acc[i][j] = __builtin_amdgcn_mfma_f32_16x16x32_bf16(afh[i], bfl[j], acc[i][j], 0, 0, 0);
        acc[i][j] = __builtin_amdgcn_mfma_f32_16x16x32_bf16(afh[i], bfh[j], acc[i][j], 0, 0, 0);
      }
    __syncthreads();
  }
  for (int i = 0; i < 4; ++i)
    for (int j = 0; j < 4; ++j)
      for (int r = 0; r < 4; ++r) {
        int row = m0 + wy * 64 + i * 16 + quad * 4 + r;
        int col = n0 + wx * 64 + j * 16 + l16;
        float a = acc[i][j][r];
        int b = row >> 11, t = row & 2047;
        if (n0 < 768) {
          int h = col >> 6, d = col & 63;
          size_t o = ((size_t)(b * 12 + h)) * 131072 + (size_t)t * 64 + d;
          bf16 hh = (bf16)a;
          qh[o] = hh;
          ql[o] = (bf16)(a - (float)hh);
        } else if (n0 < 1536) {
          int c = col - 768;
          int h = c >> 6, d = c & 63;
          size_t o = ((size_t)(b * 12 + h)) * 131072 + (size_t)t * 64 + d;
          bf16 hh = (bf16)a;
          kh[o] = hh;
          kl[o] = (bf16)(a - (float)hh);
        } else {
          int c = col - 1536;
          int h = c >> 6, d = c & 63;
          vt[((size_t)(b * 12 + h)) * 131072 + (size_t)d * 2048 + t] = (bf16)a;
        }
      }
}

// C[M,N] = A[M,K](bf16) * Bt[N,K]^T(bf16), fp32 out.
__global__ __launch_bounds__(256) void gemm_bt_f32(const bf16* __restrict__ A,
                                                   const bf16* __restrict__ Bt,
                                                   float* __restrict__ C,
                                                   int M, int N, int K) {
  __shared__ bf16 As[128 * LDT];
  __shared__ bf16 Bs[128 * LDT];
  int tid = threadIdx.x;
  int lane = tid & 63, wid = tid >> 6;
  int quad = lane >> 4, l16 = lane & 15;
  int wy = wid >> 1, wx = wid & 1;
  int m0 = blockIdx.x * 128, n0 = blockIdx.y * 128;
  int srow = tid >> 3, scol = (tid & 7) * 8;
  floatx4 acc[4][4] = {};
  for (int k0 = 0; k0 < K; k0 += 64) {
    for (int p = 0; p < 4; ++p) {
      int r = srow + p * 32;
      *(uint4*)(As + r * LDT + scol) = *(const uint4*)(A + (size_t)(m0 + r) * K + k0 + scol);
      *(uint4*)(Bs + r * LDT + scol) = *(const uint4*)(Bt + (size_t)(n0 + r) * K + k0 + scol);
    }
    __syncthreads();
    for (int kk = 0; kk < 64; kk += 32) {
      bf16x8 af[4], bfr[4];
      for (int i = 0; i < 4; ++i)
        af[i] = *(const bf16x8*)(As + (wy * 64 + i * 16 + l16) * LDT + kk + quad * 8);
      for (int j = 0; j < 4; ++j)
        bfr[j] = *(const bf16x8*)(Bs + (wx * 64 + j * 16 + l16) * LDT + kk + quad * 8);
      for (int i = 0; i < 4; ++i)
        for (int j = 0; j < 4; ++j)
          acc[i][j] = __builtin_amdgcn_mfma_f32_16x16x32_bf16(af[i], bfr[j], acc[i][j], 0, 0, 0);
    }
    __syncthreads();
  }
  for (int i = 0; i < 4; ++i) {
    int row = m0 + wy * 64 + i * 16 + quad * 4;
    for (int j = 0; j < 4; ++j) {
      int col = n0 + wx * 64 + j * 16 + l16;
      for (int r = 0; r < 4; ++r)
        C[(size_t)(row + r) * N + col] = acc[i][j][r];
    }
  }
}

// Flash attention v2. Per-head inputs already split/transposed by gemm1.
// One block per (bh, 64-row Q tile); 4 waves x 16 Q rows. LDS = 4 tiles = 36 KB
// -> 4 blocks/CU. Q frags direct global->reg; K/V staged as pure uint4 copies.
__global__ __launch_bounds__(256) void flash_attn(const bf16* __restrict__ qh,
                                                  const bf16* __restrict__ ql,
                                                  const bf16* __restrict__ kh,
                                                  const bf16* __restrict__ kl,
                                                  const bf16* __restrict__ vT,
                                                  bf16* __restrict__ y) {
  __shared__ bf16 Kh[64 * LDT], Kl[64 * LDT], Vt[64 * LDT], Ps[64 * LDT];
  const int T = 2048;
  int qt = blockIdx.x & 31, bh = blockIdx.x >> 5;
  int b = bh / 12, h = bh - b * 12;
  int tid = threadIdx.x;
  int lane = tid & 63, wid = tid >> 6;
  int quad = lane >> 4, l16 = lane & 15;
  int r0 = tid >> 3, c8 = (tid & 7) * 8;  // 32 rows x 64 cols per pass, 2 passes
  size_t hb = (size_t)bh * T * 64;

  bf16x8 qfh[2], qfl[2];
  {
    size_t qrow = hb + (size_t)(qt * 64 + wid * 16 + l16) * 64 + quad * 8;
    qfh[0] = *(const bf16x8*)(qh + qrow);
    qfh[1] = *(const bf16x8*)(qh + qrow + 32);
    qfl[0] = *(const bf16x8*)(ql + qrow);
    qfl[1] = *(const bf16x8*)(ql + qrow + 32);
  }

  float m_i[4] = {-1e30f, -1e30f, -1e30f, -1e30f};
  float l_i[4] = {0.f, 0.f, 0.f, 0.f};
  floatx4 o[4] = {};

  for (int kt = 0; kt < 32; ++kt) {
    __syncthreads();  // previous iteration's LDS reads done
    for (int p = 0; p < 2; ++p) {
      int r = r0 + p * 32;
      size_t src = hb + (size_t)(kt * 64 + r) * 64 + c8;
      *(uint4*)(Kh + r * LDT + c8) = *(const uint4*)(kh + src);
      *(uint4*)(Kl + r * LDT + c8) = *(const uint4*)(kl + src);
      *(uint4*)(Vt + r * LDT + c8) = *(const uint4*)(vT + hb + (size_t)r * T + kt * 64 + c8);
    }
    __syncthreads();

    // S = Q K^T via 3-term hi/lo split, scaled by sqrt(Dh)=8 per reference
    floatx4 sf[4];
    const floatx4 z4 = {0.f, 0.f, 0.f, 0.f};
    for (int j = 0; j < 4; ++j) sf[j] = z4;
    for (int kk = 0; kk < 2; ++kk)
      for (int j = 0; j < 4; ++j) {
        bf16x8 khf = *(const bf16x8*)(Kh + (j * 16 + l16) * LDT + kk * 32 + quad * 8);
        bf16x8 klf = *(const bf16x8*)(Kl + (j * 16 + l16) * LDT + kk * 32 + quad * 8);
        sf[j] = __builtin_amdgcn_mfma_f32_16x16x32_bf16(qfl[kk], khf, sf[j], 0, 0, 0);
        sf[j] = __builtin_amdgcn_mfma_f32_16x16x32_bf16(qfh[kk], klf, sf[j], 0, 0, 0);
        sf[j] = __builtin_amdgcn_mfma_f32_16x16x32_bf16(qfh[kk], khf, sf[j], 0, 0, 0);
      }
    for (int j = 0; j < 4; ++j) sf[j] *= 8.0f;

    // online softmax; lane holds rows quad*4+r (col l16) of its wave's strip
    for (int r = 0; r < 4; ++r) {
      float mx = fmaxf(fmaxf(sf[0][r], sf[1][r]), fmaxf(sf[2][r], sf[3][r]));
      for (int off = 1; off < 16; off <<= 1) mx = fmaxf(mx, __shfl_xor(mx, off));
      float m_new = fmaxf(m_i[r], mx);
      float alpha = __expf(m_i[r] - m_new);
      float rowsum = 0.f;
      for (int j = 0; j < 4; ++j) {
        float pv = __expf(sf[j][r] - m_new);
        sf[j][r] = pv;
        rowsum += pv;
      }
      for (int off = 1; off < 16; off <<= 1) rowsum += __shfl_xor(rowsum, off);
      l_i[r] = l_i[r] * alpha + rowsum;
      m_i[r] = m_new;
      for (int dn = 0; dn < 4; ++dn) o[dn][r] *= alpha;
    }

    // P: C-layout -> LDS -> A-layout (wave-private strip, in-order LDS per wave)
    for (int j = 0; j < 4; ++j)
      for (int r = 0; r < 4; ++r)
        Ps[(wid * 16 + quad * 4 + r) * LDT + j * 16 + l16] = (bf16)sf[j][r];
    for (int kk = 0; kk < 2; ++kk) {
      bf16x8 pf = *(const bf16x8*)(Ps + (wid * 16 + l16) * LDT + kk * 32 + quad * 8);
      for (int dn = 0; dn < 4; ++dn) {
        bf16x8 vf = *(const bf16x8*)(Vt + (dn * 16 + l16) * LDT + kk * 32 + quad * 8);
        o[dn] = __builtin_amdgcn_mfma_f32_16x16x32_bf16(pf, vf, o[dn], 0, 0, 0);
      }
    }
  }

  for (int r = 0; r < 4; ++r) {
    float invl = 1.0f / l_i[r];
    int t = qt * 64 + wid * 16 + quad * 4 + r;
    size_t off = ((size_t)(b * T + t)) * 768 + h * 64;
    for (int dn = 0; dn < 4; ++dn)
      y[off + dn * 16 + l16] = (bf16)(o[dn][r] * invl);
  }
}

extern "C" void kernel_launch(void* const* d_in, const int* in_sizes, int n_in,
                              void* d_out, int out_size, void* d_ws, size_t ws_size,
                              hipStream_t stream) {
  const float* x     = (const float*)d_in[0];  // [4,2048,768] fp32
  const float* Wqkv  = (const float*)d_in[1];  // [768,2304] fp32
  const float* Wproj = (const float*)d_in[2];  // [768,768] fp32
  float* out = (float*)d_out;                  // [4,2048,768] fp32
  char* ws = (char*)d_ws;
  bf16* qh     = (bf16*)ws;                 // 48*2048*64*2 = 12,582,912 B each
  bf16* ql     = (bf16*)(ws + 12582912);
  bf16* kh     = (bf16*)(ws + 25165824);
  bf16* kl     = (bf16*)(ws + 37748736);
  bf16* vT     = (bf16*)(ws + 50331648);
  bf16* y16    = (bf16*)(ws + 62914560);
  bf16* Bth    = (bf16*)(ws + 75497472);    // 2304*768*2 = 3,538,944 B
  bf16* Btl    = (bf16*)(ws + 79036416);
  bf16* WprojT = (bf16*)(ws + 82575360);    // 768*768*2 = 1,179,648 B
                                            // total 83,755,008 B (== R3, fits)

  transpose_split_w<<<dim3(3, 2304), 256, 0, stream>>>(Wqkv, Bth, Btl, 768, 2304);
  transpose_f32_bf16<<<dim3(3, 768), 256, 0, stream>>>(Wproj, WprojT, 768, 768);
  gemm1_split<<<dim3(64, 18), 256, 0, stream>>>(x, Bth, Btl, qh, ql, kh, kl, vT);
  flash_attn<<<1536, 256, 0, stream>>>(qh, ql, kh, kl, vT, y16);
  gemm_bt_f32<<<dim3(64, 6), 256, 0, stream>>>(y16, WprojT, out, 8192, 768, 768);
}

// Round 6
// 407.955 us; speedup vs baseline: 1.3493x; 1.1987x over previous
//
#include <hip/hip_runtime.h>

typedef _Float16 f16;
typedef f16 f16x4 __attribute__((ext_vector_type(4)));
typedef f16 f16x8 __attribute__((ext_vector_type(8)));
typedef float floatx4 __attribute__((ext_vector_type(4)));

#define LDT 72   // 64-col f16 tile stride: 2-way bank alias only (free per m136)

// x fp32 -> fp16, 4 elems/thread
__global__ __launch_bounds__(256) void convert_f32_f16(const float* __restrict__ in,
                                                       f16* __restrict__ out, int n) {
  int i = (blockIdx.x * 256 + threadIdx.x) * 4;
  if (i >= n) return;
  float4 v = *(const float4*)(in + i);
  f16x4 o = {(f16)v.x, (f16)v.y, (f16)v.z, (f16)v.w};
  *(f16x4*)(out + i) = o;
}

// W [K][N] fp32 -> Wt [N][K] fp16
__global__ __launch_bounds__(256) void transpose_f32_f16(const float* __restrict__ in,
                                                         f16* __restrict__ out,
                                                         int K, int N) {
  int k = blockIdx.x * 256 + threadIdx.x;
  int n = blockIdx.y;
  if (k < K) out[(size_t)n * K + k] = (f16)in[(size_t)k * N + n];
}

// qkv = x16 @ WqkvT^T (fp16 in, fp32 acc). Epilogue scatters per-head:
//   cols [0,768):     q16 [bh][t][64]
//   cols [768,1536):  k16 [bh][t][64]
//   cols [1536,2304): vT  [bh][64][2048] (pre-transposed)
__global__ __launch_bounds__(256) void gemm1_qkv(const f16* __restrict__ A,
                                                 const f16* __restrict__ Bt,
                                                 f16* __restrict__ q16, f16* __restrict__ k16,
                                                 f16* __restrict__ vt) {
  __shared__ f16 As[128 * LDT];
  __shared__ f16 Bs[128 * LDT];
  int tid = threadIdx.x;
  int lane = tid & 63, wid = tid >> 6;
  int quad = lane >> 4, l16 = lane & 15;
  int wy = wid >> 1, wx = wid & 1;
  int m0 = blockIdx.x * 128, n0 = blockIdx.y * 128;
  int srow = tid >> 3, scol = (tid & 7) * 8;
  floatx4 acc[4][4] = {};
  for (int k0 = 0; k0 < 768; k0 += 64) {
    for (int p = 0; p < 4; ++p) {
      int r = srow + p * 32;
      *(uint4*)(As + r * LDT + scol) = *(const uint4*)(A + (size_t)(m0 + r) * 768 + k0 + scol);
      *(uint4*)(Bs + r * LDT + scol) = *(const uint4*)(Bt + (size_t)(n0 + r) * 768 + k0 + scol);
    }
    __syncthreads();
    for (int kk = 0; kk < 64; kk += 32) {
      f16x8 af[4], bfr[4];
      for (int i = 0; i < 4; ++i)
        af[i] = *(const f16x8*)(As + (wy * 64 + i * 16 + l16) * LDT + kk + quad * 8);
      for (int j = 0; j < 4; ++j)
        bfr[j] = *(const f16x8*)(Bs + (wx * 64 + j * 16 + l16) * LDT + kk + quad * 8);
      for (int i = 0; i < 4; ++i)
        for (int j = 0; j < 4; ++j)
          acc[i][j] = __builtin_amdgcn_mfma_f32_16x16x32_f16(af[i], bfr[j], acc[i][j], 0, 0, 0);
    }
    __syncthreads();
  }
  for (int i = 0; i < 4; ++i)
    for (int j = 0; j < 4; ++j)
      for (int r = 0; r < 4; ++r) {
        int row = m0 + wy * 64 + i * 16 + quad * 4 + r;
        int col = n0 + wx * 64 + j * 16 + l16;
        float a = acc[i][j][r];
        int b = row >> 11, t = row & 2047;
        if (col < 768) {
          int h = col >> 6, d = col & 63;
          q16[((size_t)(b * 12 + h)) * 131072 + (size_t)t * 64 + d] = (f16)a;
        } else if (col < 1536) {
          int c = col - 768;
          int h = c >> 6, d = c & 63;
          k16[((size_t)(b * 12 + h)) * 131072 + (size_t)t * 64 + d] = (f16)a;
        } else {
          int c = col - 1536;
          int h = c >> 6, d = c & 63;
          vt[((size_t)(b * 12 + h)) * 131072 + (size_t)d * 2048 + t] = (f16)a;
        }
      }
}

// C[M,N](fp32) = A[M,K](f16) * Bt[N,K]^T(f16)
__global__ __launch_bounds__(256) void gemm_bt_f16(const f16* __restrict__ A,
                                                   const f16* __restrict__ Bt,
                                                   float* __restrict__ C,
                                                   int M, int N, int K) {
  __shared__ f16 As[128 * LDT];
  __shared__ f16 Bs[128 * LDT];
  int tid = threadIdx.x;
  int lane = tid & 63, wid = tid >> 6;
  int quad = lane >> 4, l16 = lane & 15;
  int wy = wid >> 1, wx = wid & 1;
  int m0 = blockIdx.x * 128, n0 = blockIdx.y * 128;
  int srow = tid >> 3, scol = (tid & 7) * 8;
  floatx4 acc[4][4] = {};
  for (int k0 = 0; k0 < K; k0 += 64) {
    for (int p = 0; p < 4; ++p) {
      int r = srow + p * 32;
      *(uint4*)(As + r * LDT + scol) = *(const uint4*)(A + (size_t)(m0 + r) * K + k0 + scol);
      *(uint4*)(Bs + r * LDT + scol) = *(const uint4*)(Bt + (size_t)(n0 + r) * K + k0 + scol);
    }
    __syncthreads();
    for (int kk = 0; kk < 64; kk += 32) {
      f16x8 af[4], bfr[4];
      for (int i = 0; i < 4; ++i)
        af[i] = *(const f16x8*)(As + (wy * 64 + i * 16 + l16) * LDT + kk + quad * 8);
      for (int j = 0; j < 4; ++j)
        bfr[j] = *(const f16x8*)(Bs + (wx * 64 + j * 16 + l16) * LDT + kk + quad * 8);
      for (int i = 0; i < 4; ++i)
        for (int j = 0; j < 4; ++j)
          acc[i][j] = __builtin_amdgcn_mfma_f32_16x16x32_f16(af[i], bfr[j], acc[i][j], 0, 0, 0);
    }
    __syncthreads();
  }
  for (int i = 0; i < 4; ++i) {
    int row = m0 + wy * 64 + i * 16 + quad * 4;
    for (int j = 0; j < 4; ++j) {
      int col = n0 + wx * 64 + j * 16 + l16;
      for (int r = 0; r < 4; ++r)
        C[(size_t)(row + r) * N + col] = acc[i][j][r];
    }
  }
}

// Flash attention v3 (fp16). One block per (bh, 64-row Q tile); 4 waves x 16 Q rows.
// LDS = 3 tiles = 27 KB -> 5 blocks/CU. Next K/V tile prefetched into registers so
// global-load latency overlaps compute instead of sitting between the two barriers.
__global__ __launch_bounds__(256) void flash_attn(const f16* __restrict__ q16,
                                                  const f16* __restrict__ k16,
                                                  const f16* __restrict__ vT,
                                                  f16* __restrict__ y) {
  __shared__ f16 Ks[64 * LDT], Vt[64 * LDT], Ps[64 * LDT];
  const int T = 2048;
  int qt = blockIdx.x & 31, bh = blockIdx.x >> 5;
  int b = bh / 12, h = bh - b * 12;
  int tid = threadIdx.x;
  int lane = tid & 63, wid = tid >> 6;
  int quad = lane >> 4, l16 = lane & 15;
  int r0 = tid >> 3, c8 = (tid & 7) * 8;  // 32 rows x 64 cols per pass, 2 passes
  size_t hb = (size_t)bh * T * 64;

  f16x8 qf[2];
  {
    size_t qrow = hb + (size_t)(qt * 64 + wid * 16 + l16) * 64 + quad * 8;
    qf[0] = *(const f16x8*)(q16 + qrow);
    qf[1] = *(const f16x8*)(q16 + qrow + 32);
  }

  float m_i[4] = {-1e30f, -1e30f, -1e30f, -1e30f};
  float l_i[4] = {0.f, 0.f, 0.f, 0.f};
  floatx4 o[4] = {};

  uint4 kr[2], vr[2];
  for (int p = 0; p < 2; ++p) {
    int r = r0 + p * 32;
    kr[p] = *(const uint4*)(k16 + hb + (size_t)r * 64 + c8);
    vr[p] = *(const uint4*)(vT + hb + (size_t)r * T + c8);
  }

  for (int kt = 0; kt < 32; ++kt) {
    __syncthreads();  // previous iteration's LDS reads done
    for (int p = 0; p < 2; ++p) {
      int r = r0 + p * 32;
      *(uint4*)(Ks + r * LDT + c8) = kr[p];
      *(uint4*)(Vt + r * LDT + c8) = vr[p];
    }
    __syncthreads();
    if (kt < 31) {  // prefetch next tile; latency overlaps compute below
      for (int p = 0; p < 2; ++p) {
        int r = r0 + p * 32;
        kr[p] = *(const uint4*)(k16 + hb + (size_t)((kt + 1) * 64 + r) * 64 + c8);
        vr[p] = *(const uint4*)(vT + hb + (size_t)r * T + (kt + 1) * 64 + c8);
      }
    }

    // S = Q K^T, scaled by sqrt(Dh)=8 per reference
    floatx4 sf[4];
    const floatx4 z4 = {0.f, 0.f, 0.f, 0.f};
    for (int j = 0; j < 4; ++j) sf[j] = z4;
    for (int kk = 0; kk < 2; ++kk)
      for (int j = 0; j < 4; ++j) {
        f16x8 kf = *(const f16x8*)(Ks + (j * 16 + l16) * LDT + kk * 32 + quad * 8);
        sf[j] = __builtin_amdgcn_mfma_f32_16x16x32_f16(qf[kk], kf, sf[j], 0, 0, 0);
      }
    for (int j = 0; j < 4; ++j) sf[j] *= 8.0f;

    // online softmax; lane holds rows quad*4+r (col l16) of its wave's strip
    for (int r = 0; r < 4; ++r) {
      float mx = fmaxf(fmaxf(sf[0][r], sf[1][r]), fmaxf(sf[2][r], sf[3][r]));
      for (int off = 1; off < 16; off <<= 1) mx = fmaxf(mx, __shfl_xor(mx, off));
      float m_new = fmaxf(m_i[r], mx);
      float alpha = __expf(m_i[r] - m_new);
      float rowsum = 0.f;
      for (int j = 0; j < 4; ++j) {
        float pv = __expf(sf[j][r] - m_new);
        sf[j][r] = pv;
        rowsum += pv;
      }
      for (int off = 1; off < 16; off <<= 1) rowsum += __shfl_xor(rowsum, off);
      l_i[r] = l_i[r] * alpha + rowsum;
      m_i[r] = m_new;
      for (int dn = 0; dn < 4; ++dn) o[dn][r] *= alpha;
    }

    // P: C-layout -> LDS -> A-layout (wave-private strip, in-order LDS per wave)
    for (int j = 0; j < 4; ++j)
      for (int r = 0; r < 4; ++r)
        Ps[(wid * 16 + quad * 4 + r) * LDT + j * 16 + l16] = (f16)sf[j][r];
    for (int kk = 0; kk < 2; ++kk) {
      f16x8 pf = *(const f16x8*)(Ps + (wid * 16 + l16) * LDT + kk * 32 + quad * 8);
      for (int dn = 0; dn < 4; ++dn) {
        f16x8 vf = *(const f16x8*)(Vt + (dn * 16 + l16) * LDT + kk * 32 + quad * 8);
        o[dn] = __builtin_amdgcn_mfma_f32_16x16x32_f16(pf, vf, o[dn], 0, 0, 0);
      }
    }
  }

  for (int r = 0; r < 4; ++r) {
    float invl = 1.0f / l_i[r];
    int t = qt * 64 + wid * 16 + quad * 4 + r;
    size_t off = ((size_t)(b * T + t)) * 768 + h * 64;
    for (int dn = 0; dn < 4; ++dn)
      y[off + dn * 16 + l16] = (f16)(o[dn][r] * invl);
  }
}

extern "C" void kernel_launch(void* const* d_in, const int* in_sizes, int n_in,
                              void* d_out, int out_size, void* d_ws, size_t ws_size,
                              hipStream_t stream) {
  const float* x     = (const float*)d_in[0];  // [4,2048,768] fp32
  const float* Wqkv  = (const float*)d_in[1];  // [768,2304] fp32
  const float* Wproj = (const float*)d_in[2];  // [768,768] fp32
  float* out = (float*)d_out;                  // [4,2048,768] fp32
  char* ws = (char*)d_ws;
  f16* x16    = (f16*)ws;                  // 8192*768*2 = 12,582,912 B each
  f16* q16    = (f16*)(ws + 12582912);
  f16* k16    = (f16*)(ws + 25165824);
  f16* vT16   = (f16*)(ws + 37748736);
  f16* y16    = (f16*)(ws + 50331648);
  f16* WqkvT  = (f16*)(ws + 62914560);     // 2304*768*2 = 3,538,944 B
  f16* WprojT = (f16*)(ws + 66453504);     //  768*768*2 = 1,179,648 B
                                           // total 67,633,152 B (< R3's 83.7MB, fits)

  convert_f32_f16<<<6144, 256, 0, stream>>>(x, x16, 6291456);
  transpose_f32_f16<<<dim3(3, 2304), 256, 0, stream>>>(Wqkv, WqkvT, 768, 2304);
  transpose_f32_f16<<<dim3(3, 768), 256, 0, stream>>>(Wproj, WprojT, 768, 768);
  gemm1_qkv<<<dim3(64, 18), 256, 0, stream>>>(x16, WqkvT, q16, k16, vT16);
  flash_attn<<<1536, 256, 0, stream>>>(q16, k16, vT16, y16);
  gemm_bt_f16<<<dim3(64, 6), 256, 0, stream>>>(y16, WprojT, out, 8192, 768, 768);
}

// Round 7
// 331.352 us; speedup vs baseline: 1.6613x; 1.2312x over previous
//
#include <hip/hip_runtime.h>

typedef _Float16 f16;
typedef f16 f16x4 __attribute__((ext_vector_type(4)));
typedef f16 f16x8 __attribute__((ext_vector_type(8)));
typedef float floatx4 __attribute__((ext_vector_type(4)));

#define LDT 72   // 64-col f16 tile stride: 2-way bank alias only (free per m136)
#define QSCALE 11.5415603271117f  // 8 * log2(e): score computed in log2 domain

// x fp32 -> fp16, 4 elems/thread
__global__ __launch_bounds__(256) void convert_f32_f16(const float* __restrict__ in,
                                                       f16* __restrict__ out, int n) {
  int i = (blockIdx.x * 256 + threadIdx.x) * 4;
  if (i >= n) return;
  float4 v = *(const float4*)(in + i);
  f16x4 o = {(f16)v.x, (f16)v.y, (f16)v.z, (f16)v.w};
  *(f16x4*)(out + i) = o;
}

// W [K][N] fp32 -> Wt [N][K] fp16
__global__ __launch_bounds__(256) void transpose_f32_f16(const float* __restrict__ in,
                                                         f16* __restrict__ out,
                                                         int K, int N) {
  int k = blockIdx.x * 256 + threadIdx.x;
  int n = blockIdx.y;
  if (k < K) out[(size_t)n * K + k] = (f16)in[(size_t)k * N + n];
}

// qkv = x16 @ WqkvT^T (fp16 in, fp32 acc). Epilogue scatters per-head:
//   cols [0,768):     q16 [bh][t][64], PRE-SCALED by 8*log2(e)
//   cols [768,1536):  k16 [bh][t][64]
//   cols [1536,2304): vT  [bh][64][2048] (pre-transposed)
__global__ __launch_bounds__(256) void gemm1_qkv(const f16* __restrict__ A,
                                                 const f16* __restrict__ Bt,
                                                 f16* __restrict__ q16, f16* __restrict__ k16,
                                                 f16* __restrict__ vt) {
  __shared__ f16 As[128 * LDT];
  __shared__ f16 Bs[128 * LDT];
  int tid = threadIdx.x;
  int lane = tid & 63, wid = tid >> 6;
  int quad = lane >> 4, l16 = lane & 15;
  int wy = wid >> 1, wx = wid & 1;
  int m0 = blockIdx.x * 128, n0 = blockIdx.y * 128;
  int srow = tid >> 3, scol = (tid & 7) * 8;
  floatx4 acc[4][4] = {};
  for (int k0 = 0; k0 < 768; k0 += 64) {
    for (int p = 0; p < 4; ++p) {
      int r = srow + p * 32;
      *(uint4*)(As + r * LDT + scol) = *(const uint4*)(A + (size_t)(m0 + r) * 768 + k0 + scol);
      *(uint4*)(Bs + r * LDT + scol) = *(const uint4*)(Bt + (size_t)(n0 + r) * 768 + k0 + scol);
    }
    __syncthreads();
    for (int kk = 0; kk < 64; kk += 32) {
      f16x8 af[4], bfr[4];
      for (int i = 0; i < 4; ++i)
        af[i] = *(const f16x8*)(As + (wy * 64 + i * 16 + l16) * LDT + kk + quad * 8);
      for (int j = 0; j < 4; ++j)
        bfr[j] = *(const f16x8*)(Bs + (wx * 64 + j * 16 + l16) * LDT + kk + quad * 8);
      for (int i = 0; i < 4; ++i)
        for (int j = 0; j < 4; ++j)
          acc[i][j] = __builtin_amdgcn_mfma_f32_16x16x32_f16(af[i], bfr[j], acc[i][j], 0, 0, 0);
    }
    __syncthreads();
  }
  for (int i = 0; i < 4; ++i)
    for (int j = 0; j < 4; ++j)
      for (int r = 0; r < 4; ++r) {
        int row = m0 + wy * 64 + i * 16 + quad * 4 + r;
        int col = n0 + wx * 64 + j * 16 + l16;
        float a = acc[i][j][r];
        int b = row >> 11, t = row & 2047;
        if (col < 768) {
          int h = col >> 6, d = col & 63;
          q16[((size_t)(b * 12 + h)) * 131072 + (size_t)t * 64 + d] = (f16)(a * QSCALE);
        } else if (col < 1536) {
          int c = col - 768;
          int h = c >> 6, d = c & 63;
          k16[((size_t)(b * 12 + h)) * 131072 + (size_t)t * 64 + d] = (f16)a;
        } else {
          int c = col - 1536;
          int h = c >> 6, d = c & 63;
          vt[((size_t)(b * 12 + h)) * 131072 + (size_t)d * 2048 + t] = (f16)a;
        }
      }
}

// C[M,N](fp32) = A[M,K](f16) * Bt[N,K]^T(f16)
__global__ __launch_bounds__(256) void gemm_bt_f16(const f16* __restrict__ A,
                                                   const f16* __restrict__ Bt,
                                                   float* __restrict__ C,
                                                   int M, int N, int K) {
  __shared__ f16 As[128 * LDT];
  __shared__ f16 Bs[128 * LDT];
  int tid = threadIdx.x;
  int lane = tid & 63, wid = tid >> 6;
  int quad = lane >> 4, l16 = lane & 15;
  int wy = wid >> 1, wx = wid & 1;
  int m0 = blockIdx.x * 128, n0 = blockIdx.y * 128;
  int srow = tid >> 3, scol = (tid & 7) * 8;
  floatx4 acc[4][4] = {};
  for (int k0 = 0; k0 < K; k0 += 64) {
    for (int p = 0; p < 4; ++p) {
      int r = srow + p * 32;
      *(uint4*)(As + r * LDT + scol) = *(const uint4*)(A + (size_t)(m0 + r) * K + k0 + scol);
      *(uint4*)(Bs + r * LDT + scol) = *(const uint4*)(Bt + (size_t)(n0 + r) * K + k0 + scol);
    }
    __syncthreads();
    for (int kk = 0; kk < 64; kk += 32) {
      f16x8 af[4], bfr[4];
      for (int i = 0; i < 4; ++i)
        af[i] = *(const f16x8*)(As + (wy * 64 + i * 16 + l16) * LDT + kk + quad * 8);
      for (int j = 0; j < 4; ++j)
        bfr[j] = *(const f16x8*)(Bs + (wx * 64 + j * 16 + l16) * LDT + kk + quad * 8);
      for (int i = 0; i < 4; ++i)
        for (int j = 0; j < 4; ++j)
          acc[i][j] = __builtin_amdgcn_mfma_f32_16x16x32_f16(af[i], bfr[j], acc[i][j], 0, 0, 0);
    }
    __syncthreads();
  }
  for (int i = 0; i < 4; ++i) {
    int row = m0 + wy * 64 + i * 16 + quad * 4;
    for (int j = 0; j < 4; ++j) {
      int col = n0 + wx * 64 + j * 16 + l16;
      for (int r = 0; r < 4; ++r)
        C[(size_t)(row + r) * N + col] = acc[i][j][r];
    }
  }
}

// Flash attention v4 (fp16, log2-domain softmax, LDS double-buffer, XCD remap).
// One block per (bh, 64-row Q tile); 4 waves x 16 Q rows. LDS 46 KB -> 3 blocks/CU.
__global__ __launch_bounds__(256, 2) void flash_attn(const f16* __restrict__ q16,
                                                     const f16* __restrict__ k16,
                                                     const f16* __restrict__ vT,
                                                     f16* __restrict__ y) {
  __shared__ f16 Ks[2][64 * LDT], Vt[2][64 * LDT], Ps[64 * LDT];
  const int T = 2048;
  // XCD-locality remap: blocks with the same head share an XCD's L2 (8 XCDs, 48 heads)
  int xcd = blockIdx.x & 7, yb = blockIdx.x >> 3;
  int bh = xcd * 6 + (yb >> 5);
  int qt = yb & 31;
  int b = bh / 12, h = bh - b * 12;
  int tid = threadIdx.x;
  int lane = tid & 63, wid = tid >> 6;
  int quad = lane >> 4, l16 = lane & 15;
  int r0 = tid >> 3, c8 = (tid & 7) * 8;  // 32 rows x 64 cols per pass, 2 passes
  size_t hb = (size_t)bh * T * 64;

  f16x8 qf[2];
  {
    size_t qrow = hb + (size_t)(qt * 64 + wid * 16 + l16) * 64 + quad * 8;
    qf[0] = *(const f16x8*)(q16 + qrow);
    qf[1] = *(const f16x8*)(q16 + qrow + 32);
  }
  f16x8 ones;
  for (int e = 0; e < 8; ++e) ones[e] = (f16)1.0f;

  float m_i[4] = {-1e30f, -1e30f, -1e30f, -1e30f};
  float l_i[4] = {0.f, 0.f, 0.f, 0.f};
  floatx4 o[4] = {};

  // stage tile 0 into buffer 0
  for (int p = 0; p < 2; ++p) {
    int r = r0 + p * 32;
    *(uint4*)(Ks[0] + r * LDT + c8) = *(const uint4*)(k16 + hb + (size_t)r * 64 + c8);
    *(uint4*)(Vt[0] + r * LDT + c8) = *(const uint4*)(vT + hb + (size_t)r * T + c8);
  }
  int cur = 0;

  for (int kt = 0; kt < 32; ++kt) {
    __syncthreads();  // buf[cur] ready; prior reads of buf[cur^1] complete
    if (kt < 31) {    // stage next tile; load latency overlaps compute below
      for (int p = 0; p < 2; ++p) {
        int r = r0 + p * 32;
        uint4 kv = *(const uint4*)(k16 + hb + (size_t)((kt + 1) * 64 + r) * 64 + c8);
        uint4 vv = *(const uint4*)(vT + hb + (size_t)r * T + (kt + 1) * 64 + c8);
        *(uint4*)(Ks[cur ^ 1] + r * LDT + c8) = kv;
        *(uint4*)(Vt[cur ^ 1] + r * LDT + c8) = vv;
      }
    }
    const f16* Kc = Ks[cur];
    const f16* Vc = Vt[cur];

    // t = (8*log2e) * q.k  — log2-domain scores
    floatx4 sf[4];
    const floatx4 z4 = {0.f, 0.f, 0.f, 0.f};
    for (int j = 0; j < 4; ++j) sf[j] = z4;
    for (int kk = 0; kk < 2; ++kk)
      for (int j = 0; j < 4; ++j) {
        f16x8 kf = *(const f16x8*)(Kc + (j * 16 + l16) * LDT + kk * 32 + quad * 8);
        sf[j] = __builtin_amdgcn_mfma_f32_16x16x32_f16(qf[kk], kf, sf[j], 0, 0, 0);
      }

    // online softmax (base 2); lane holds rows quad*4+r (col l16) of its strip
    float alpha[4];
    for (int r = 0; r < 4; ++r) {
      float mx = fmaxf(fmaxf(sf[0][r], sf[1][r]), fmaxf(sf[2][r], sf[3][r]));
      for (int off = 1; off < 16; off <<= 1) mx = fmaxf(mx, __shfl_xor(mx, off));
      float m_new = fmaxf(m_i[r], mx);
      alpha[r] = exp2f(m_i[r] - m_new);
      m_i[r] = m_new;
      for (int j = 0; j < 4; ++j) sf[j][r] = exp2f(sf[j][r] - m_new);
      for (int dn = 0; dn < 4; ++dn) o[dn][r] *= alpha[r];
    }

    // P: C-layout -> LDS -> A-layout (wave-private strip)
    for (int j = 0; j < 4; ++j)
      for (int r = 0; r < 4; ++r)
        Ps[(wid * 16 + quad * 4 + r) * LDT + j * 16 + l16] = (f16)sf[j][r];
    floatx4 rs = z4;  // row sums via MFMA against ones (replaces 16 shfl ops)
    for (int kk = 0; kk < 2; ++kk) {
      f16x8 pf = *(const f16x8*)(Ps + (wid * 16 + l16) * LDT + kk * 32 + quad * 8);
      rs = __builtin_amdgcn_mfma_f32_16x16x32_f16(pf, ones, rs, 0, 0, 0);
      for (int dn = 0; dn < 4; ++dn) {
        f16x8 vf = *(const f16x8*)(Vc + (dn * 16 + l16) * LDT + kk * 32 + quad * 8);
        o[dn] = __builtin_amdgcn_mfma_f32_16x16x32_f16(pf, vf, o[dn], 0, 0, 0);
      }
    }
    for (int r = 0; r < 4; ++r) l_i[r] = l_i[r] * alpha[r] + rs[r];
    cur ^= 1;
  }

  for (int r = 0; r < 4; ++r) {
    float invl = 1.0f / l_i[r];
    int t = qt * 64 + wid * 16 + quad * 4 + r;
    size_t off = ((size_t)(b * T + t)) * 768 + h * 64;
    for (int dn = 0; dn < 4; ++dn)
      y[off + dn * 16 + l16] = (f16)(o[dn][r] * invl);
  }
}

extern "C" void kernel_launch(void* const* d_in, const int* in_sizes, int n_in,
                              void* d_out, int out_size, void* d_ws, size_t ws_size,
                              hipStream_t stream) {
  const float* x     = (const float*)d_in[0];  // [4,2048,768] fp32
  const float* Wqkv  = (const float*)d_in[1];  // [768,2304] fp32
  const float* Wproj = (const float*)d_in[2];  // [768,768] fp32
  float* out = (float*)d_out;                  // [4,2048,768] fp32
  char* ws = (char*)d_ws;
  f16* x16    = (f16*)ws;                  // 8192*768*2 = 12,582,912 B each
  f16* q16    = (f16*)(ws + 12582912);
  f16* k16    = (f16*)(ws + 25165824);
  f16* vT16   = (f16*)(ws + 37748736);
  f16* y16    = (f16*)(ws + 50331648);
  f16* WqkvT  = (f16*)(ws + 62914560);     // 2304*768*2 = 3,538,944 B
  f16* WprojT = (f16*)(ws + 66453504);     //  768*768*2 = 1,179,648 B
                                           // total 67,633,152 B

  convert_f32_f16<<<6144, 256, 0, stream>>>(x, x16, 6291456);
  transpose_f32_f16<<<dim3(3, 2304), 256, 0, stream>>>(Wqkv, WqkvT, 768, 2304);
  transpose_f32_f16<<<dim3(3, 768), 256, 0, stream>>>(Wproj, WprojT, 768, 768);
  gemm1_qkv<<<dim3(64, 18), 256, 0, stream>>>(x16, WqkvT, q16, k16, vT16);
  flash_attn<<<1536, 256, 0, stream>>>(q16, k16, vT16, y16);
  gemm_bt_f16<<<dim3(64, 6), 256, 0, stream>>>(y16, WprojT, out, 8192, 768, 768);
}

// Round 10
// 284.800 us; speedup vs baseline: 1.9328x; 1.1635x over previous
//
#include <hip/hip_runtime.h>

typedef _Float16 f16;
typedef f16 f16x4 __attribute__((ext_vector_type(4)));
typedef f16 f16x8 __attribute__((ext_vector_type(8)));
typedef float floatx4 __attribute__((ext_vector_type(4)));

#define LDT 72   // 64-col f16 tile stride: 2-way bank alias only (free per m136)
#define QSCALE 11.5415603271117f  // 8 * log2(e): score computed in log2 domain

// x fp32 -> fp16, 4 elems/thread
__global__ __launch_bounds__(256) void convert_f32_f16(const float* __restrict__ in,
                                                       f16* __restrict__ out, int n) {
  int i = (blockIdx.x * 256 + threadIdx.x) * 4;
  if (i >= n) return;
  float4 v = *(const float4*)(in + i);
  f16x4 o = {(f16)v.x, (f16)v.y, (f16)v.z, (f16)v.w};
  *(f16x4*)(out + i) = o;
}

// W [K][N] fp32 -> Wt [N][K] fp16
__global__ __launch_bounds__(256) void transpose_f32_f16(const float* __restrict__ in,
                                                         f16* __restrict__ out,
                                                         int K, int N) {
  int k = blockIdx.x * 256 + threadIdx.x;
  int n = blockIdx.y;
  if (k < K) out[(size_t)n * K + k] = (f16)in[(size_t)k * N + n];
}

// qkv = x16 @ WqkvT^T (fp16 in, fp32 acc). Epilogue scatters per-head:
//   cols [0,768):     q16 [bh][t][64], PRE-SCALED by 8*log2(e)
//   cols [768,1536):  k16 [bh][t][64]
//   cols [1536,2304): vT  [bh][64][2048] (pre-transposed)
__global__ __launch_bounds__(256) void gemm1_qkv(const f16* __restrict__ A,
                                                 const f16* __restrict__ Bt,
                                                 f16* __restrict__ q16, f16* __restrict__ k16,
                                                 f16* __restrict__ vt) {
  __shared__ f16 As[128 * LDT];
  __shared__ f16 Bs[128 * LDT];
  int tid = threadIdx.x;
  int lane = tid & 63, wid = tid >> 6;
  int quad = lane >> 4, l16 = lane & 15;
  int wy = wid >> 1, wx = wid & 1;
  int m0 = blockIdx.x * 128, n0 = blockIdx.y * 128;
  int srow = tid >> 3, scol = (tid & 7) * 8;
  floatx4 acc[4][4] = {};
  for (int k0 = 0; k0 < 768; k0 += 64) {
    for (int p = 0; p < 4; ++p) {
      int r = srow + p * 32;
      *(uint4*)(As + r * LDT + scol) = *(const uint4*)(A + (size_t)(m0 + r) * 768 + k0 + scol);
      *(uint4*)(Bs + r * LDT + scol) = *(const uint4*)(Bt + (size_t)(n0 + r) * 768 + k0 + scol);
    }
    __syncthreads();
    for (int kk = 0; kk < 64; kk += 32) {
      f16x8 af[4], bfr[4];
      for (int i = 0; i < 4; ++i)
        af[i] = *(const f16x8*)(As + (wy * 64 + i * 16 + l16) * LDT + kk + quad * 8);
      for (int j = 0; j < 4; ++j)
        bfr[j] = *(const f16x8*)(Bs + (wx * 64 + j * 16 + l16) * LDT + kk + quad * 8);
      for (int i = 0; i < 4; ++i)
        for (int j = 0; j < 4; ++j)
          acc[i][j] = __builtin_amdgcn_mfma_f32_16x16x32_f16(af[i], bfr[j], acc[i][j], 0, 0, 0);
    }
    __syncthreads();
  }
  for (int i = 0; i < 4; ++i)
    for (int j = 0; j < 4; ++j)
      for (int r = 0; r < 4; ++r) {
        int row = m0 + wy * 64 + i * 16 + quad * 4 + r;
        int col = n0 + wx * 64 + j * 16 + l16;
        float a = acc[i][j][r];
        int b = row >> 11, t = row & 2047;
        if (col < 768) {
          int h = col >> 6, d = col & 63;
          q16[((size_t)(b * 12 + h)) * 131072 + (size_t)t * 64 + d] = (f16)(a * QSCALE);
        } else if (col < 1536) {
          int c = col - 768;
          int h = c >> 6, d = c & 63;
          k16[((size_t)(b * 12 + h)) * 131072 + (size_t)t * 64 + d] = (f16)a;
        } else {
          int c = col - 1536;
          int h = c >> 6, d = c & 63;
          vt[((size_t)(b * 12 + h)) * 131072 + (size_t)d * 2048 + t] = (f16)a;
        }
      }
}

// C[M,N](fp32) = A[M,K](f16) * Bt[N,K]^T(f16)
__global__ __launch_bounds__(256) void gemm_bt_f16(const f16* __restrict__ A,
                                                   const f16* __restrict__ Bt,
                                                   float* __restrict__ C,
                                                   int M, int N, int K) {
  __shared__ f16 As[128 * LDT];
  __shared__ f16 Bs[128 * LDT];
  int tid = threadIdx.x;
  int lane = tid & 63, wid = tid >> 6;
  int quad = lane >> 4, l16 = lane & 15;
  int wy = wid >> 1, wx = wid & 1;
  int m0 = blockIdx.x * 128, n0 = blockIdx.y * 128;
  int srow = tid >> 3, scol = (tid & 7) * 8;
  floatx4 acc[4][4] = {};
  for (int k0 = 0; k0 < K; k0 += 64) {
    for (int p = 0; p < 4; ++p) {
      int r = srow + p * 32;
      *(uint4*)(As + r * LDT + scol) = *(const uint4*)(A + (size_t)(m0 + r) * K + k0 + scol);
      *(uint4*)(Bs + r * LDT + scol) = *(const uint4*)(Bt + (size_t)(n0 + r) * K + k0 + scol);
    }
    __syncthreads();
    for (int kk = 0; kk < 64; kk += 32) {
      f16x8 af[4], bfr[4];
      for (int i = 0; i < 4; ++i)
        af[i] = *(const f16x8*)(As + (wy * 64 + i * 16 + l16) * LDT + kk + quad * 8);
      for (int j = 0; j < 4; ++j)
        bfr[j] = *(const f16x8*)(Bs + (wx * 64 + j * 16 + l16) * LDT + kk + quad * 8);
      for (int i = 0; i < 4; ++i)
        for (int j = 0; j < 4; ++j)
          acc[i][j] = __builtin_amdgcn_mfma_f32_16x16x32_f16(af[i], bfr[j], acc[i][j], 0, 0, 0);
    }
    __syncthreads();
  }
  for (int i = 0; i < 4; ++i) {
    int row = m0 + wy * 64 + i * 16 + quad * 4;
    for (int j = 0; j < 4; ++j) {
      int col = n0 + wx * 64 + j * 16 + l16;
      for (int r = 0; r < 4; ++r)
        C[(size_t)(row + r) * N + col] = acc[i][j][r];
    }
  }
}

// Flash attention v5: S^T orientation. Per wave: S^T tile = 64 s-rows x 16 m-cols,
// m = lane&15 -> softmax state is scalar-per-lane; P^T (C-layout, s=quad*4+reg)
// matches the 16x16x16 B-operand k-layout (k=quad*4+j) -> PV needs NO LDS
// round-trip, just in-lane f32->f16 converts. O accumulated as O^T (dn=quad*4+reg).
// LDS = 2x(K,V) dbuf = 36 KB -> 4 blocks/CU.
__global__ __launch_bounds__(256, 2) void flash_attn(const f16* __restrict__ q16,
                                                     const f16* __restrict__ k16,
                                                     const f16* __restrict__ vT,
                                                     f16* __restrict__ y) {
  __shared__ f16 Ks[2][64 * LDT], Vt[2][64 * LDT];
  const int T = 2048;
  // XCD-locality remap: all 32 q-tiles of a head land on one XCD's L2
  int xcd = blockIdx.x & 7, yb = blockIdx.x >> 3;
  int bh = xcd * 6 + (yb >> 5);
  int qt = yb & 31;
  int b = bh / 12, h = bh - b * 12;
  int tid = threadIdx.x;
  int lane = tid & 63, wid = tid >> 6;
  int quad = lane >> 4, l16 = lane & 15;
  int r0 = tid >> 3, c8 = (tid & 7) * 8;
  size_t hb = (size_t)bh * T * 64;

  f16x8 qf[2];  // B-operand: col m = l16 -> Q row (qt*64 + wid*16 + l16)
  {
    size_t qrow = hb + (size_t)(qt * 64 + wid * 16 + l16) * 64 + quad * 8;
    qf[0] = *(const f16x8*)(q16 + qrow);
    qf[1] = *(const f16x8*)(q16 + qrow + 32);
  }
  f16x4 ones4;
  for (int e = 0; e < 4; ++e) ones4[e] = (f16)1.0f;

  float m_i = -1e30f, l_i = 0.f;
  floatx4 o[4] = {};  // O^T: dn = i*16 + quad*4 + reg, m = l16

  for (int p = 0; p < 2; ++p) {  // stage tile 0 into buffer 0
    int r = r0 + p * 32;
    *(uint4*)(Ks[0] + r * LDT + c8) = *(const uint4*)(k16 + hb + (size_t)r * 64 + c8);
    *(uint4*)(Vt[0] + r * LDT + c8) = *(const uint4*)(vT + hb + (size_t)r * T + c8);
  }
  int cur = 0;

  for (int kt = 0; kt < 32; ++kt) {
    __syncthreads();  // buf[cur] ready; prior reads of buf[cur^1] complete
    if (kt < 31) {    // stage next tile; load latency overlaps compute below
      for (int p = 0; p < 2; ++p) {
        int r = r0 + p * 32;
        uint4 kv = *(const uint4*)(k16 + hb + (size_t)((kt + 1) * 64 + r) * 64 + c8);
        uint4 vv = *(const uint4*)(vT + hb + (size_t)r * T + (kt + 1) * 64 + c8);
        *(uint4*)(Ks[cur ^ 1] + r * LDT + c8) = kv;
        *(uint4*)(Vt[cur ^ 1] + r * LDT + c8) = vv;
      }
    }
    const f16* Kc = Ks[cur];
    const f16* Vc = Vt[cur];

    // S^T[s][m] = (8*log2e) * k.q : A-frag = K rows (s), B-frag = Q (m)
    floatx4 sf[4];
    const floatx4 z4 = {0.f, 0.f, 0.f, 0.f};
    for (int i = 0; i < 4; ++i) sf[i] = z4;
    for (int kk = 0; kk < 2; ++kk)
      for (int i = 0; i < 4; ++i) {
        f16x8 kf = *(const f16x8*)(Kc + (i * 16 + l16) * LDT + kk * 32 + quad * 8);
        sf[i] = __builtin_amdgcn_mfma_f32_16x16x32_f16(kf, qf[kk], sf[i], 0, 0, 0);
      }

    // online softmax over s (base 2): 16 in-lane values + cross-quad butterfly
    float mx = fmaxf(fmaxf(sf[0][0], sf[0][1]), fmaxf(sf[0][2], sf[0][3]));
    for (int i = 1; i < 4; ++i)
      mx = fmaxf(mx, fmaxf(fmaxf(sf[i][0], sf[i][1]), fmaxf(sf[i][2], sf[i][3])));
    mx = fmaxf(mx, __shfl_xor(mx, 16));
    mx = fmaxf(mx, __shfl_xor(mx, 32));
    float m_new = fmaxf(m_i, mx);
    float alpha = exp2f(m_i - m_new);
    m_i = m_new;
    for (int i = 0; i < 4; ++i)
      for (int r = 0; r < 4; ++r) sf[i][r] = exp2f(sf[i][r] - m_new);
    for (int i = 0; i < 4; ++i) o[i] *= alpha;

    // pack P^T into 16x16x16 B-operands: k = quad*4 + j == C-layout s = quad*4 + reg
    f16x4 pf[4];
    for (int i = 0; i < 4; ++i)
      for (int r = 0; r < 4; ++r) pf[i][r] = (f16)sf[i][r];

    // row sums via ones-MFMA (every lane gets full sum over s)
    floatx4 rs = z4;
    for (int si = 0; si < 4; ++si)
      rs = __builtin_amdgcn_mfma_f32_16x16x16f16(ones4, pf[si], rs, 0, 0, 0);
    l_i = l_i * alpha + rs[0];

    // O^T += V^T . P^T : A-frag = Vt rows (dn), B-frag = pf
    for (int i = 0; i < 4; ++i)
      for (int si = 0; si < 4; ++si) {
        f16x4 vf = *(const f16x4*)(Vc + (i * 16 + l16) * LDT + si * 16 + quad * 4);
        o[i] = __builtin_amdgcn_mfma_f32_16x16x16f16(vf, pf[si], o[i], 0, 0, 0);
      }
    cur ^= 1;
  }

  // epilogue: O^T[dn][m] -> y[b, t=qt*64+wid*16+l16, h*64+dn]
  float invl = 1.0f / l_i;
  int t = qt * 64 + wid * 16 + l16;
  size_t off = ((size_t)(b * T + t)) * 768 + h * 64;
  for (int i = 0; i < 4; ++i)
    for (int r = 0; r < 4; ++r)
      y[off + i * 16 + quad * 4 + r] = (f16)(o[i][r] * invl);
}

extern "C" void kernel_launch(void* const* d_in, const int* in_sizes, int n_in,
                              void* d_out, int out_size, void* d_ws, size_t ws_size,
                              hipStream_t stream) {
  const float* x     = (const float*)d_in[0];  // [4,2048,768] fp32
  const float* Wqkv  = (const float*)d_in[1];  // [768,2304] fp32
  const float* Wproj = (const float*)d_in[2];  // [768,768] fp32
  float* out = (float*)d_out;                  // [4,2048,768] fp32
  char* ws = (char*)d_ws;
  f16* x16    = (f16*)ws;                  // 8192*768*2 = 12,582,912 B each
  f16* q16    = (f16*)(ws + 12582912);
  f16* k16    = (f16*)(ws + 25165824);
  f16* vT16   = (f16*)(ws + 37748736);
  f16* y16    = (f16*)(ws + 50331648);
  f16* WqkvT  = (f16*)(ws + 62914560);     // 2304*768*2 = 3,538,944 B
  f16* WprojT = (f16*)(ws + 66453504);     //  768*768*2 = 1,179,648 B
                                           // total 67,633,152 B

  convert_f32_f16<<<6144, 256, 0, stream>>>(x, x16, 6291456);
  transpose_f32_f16<<<dim3(3, 2304), 256, 0, stream>>>(Wqkv, WqkvT, 768, 2304);
  transpose_f32_f16<<<dim3(3, 768), 256, 0, stream>>>(Wproj, WprojT, 768, 768);
  gemm1_qkv<<<dim3(64, 18), 256, 0, stream>>>(x16, WqkvT, q16, k16, vT16);
  flash_attn<<<1536, 256, 0, stream>>>(q16, k16, vT16, y16);
  gemm_bt_f16<<<dim3(64, 6), 256, 0, stream>>>(y16, WprojT, out, 8192, 768, 768);
}

// Round 11
// 275.088 us; speedup vs baseline: 2.0011x; 1.0353x over previous
//
#include <hip/hip_runtime.h>

typedef _Float16 f16;
typedef f16 f16x4 __attribute__((ext_vector_type(4)));
typedef f16 f16x8 __attribute__((ext_vector_type(8)));
typedef __fp16 h16x2 __attribute__((ext_vector_type(2)));
typedef float floatx4 __attribute__((ext_vector_type(4)));

#define LDT 72    // 64-col f16 tile stride: 2-way bank alias only (free per m136)
#define LDTV 136  // 128-col f16 tile stride
#define QSCALE 11.5415603271117f  // 8 * log2(e): score computed in log2 domain

// x fp32 -> fp16, 4 elems/thread
__global__ __launch_bounds__(256) void convert_f32_f16(const float* __restrict__ in,
                                                       f16* __restrict__ out, int n) {
  int i = (blockIdx.x * 256 + threadIdx.x) * 4;
  if (i >= n) return;
  float4 v = *(const float4*)(in + i);
  f16x4 o = {(f16)v.x, (f16)v.y, (f16)v.z, (f16)v.w};
  *(f16x4*)(out + i) = o;
}

// W [K][N] fp32 -> Wt [N][K] fp16, 64x64 tiles via LDS: coalesced both sides
__global__ __launch_bounds__(256) void transpose_f32_f16_tiled(const float* __restrict__ in,
                                                               f16* __restrict__ out,
                                                               int K, int N) {
  __shared__ f16 tile[64][LDT];
  int k0 = blockIdx.x * 64, n0 = blockIdx.y * 64;
  int tid = threadIdx.x;
  int r = tid >> 4, c4 = (tid & 15) * 4;
  for (int p = 0; p < 4; ++p) {
    int rr = r + p * 16;
    float4 v = *(const float4*)(in + (size_t)(k0 + rr) * N + n0 + c4);
    tile[c4 + 0][rr] = (f16)v.x;
    tile[c4 + 1][rr] = (f16)v.y;
    tile[c4 + 2][rr] = (f16)v.z;
    tile[c4 + 3][rr] = (f16)v.w;
  }
  __syncthreads();
  int rn = tid >> 3, ck = (tid & 7) * 8;
  for (int p = 0; p < 2; ++p) {
    int rr = rn + p * 32;
    *(uint4*)(out + (size_t)(n0 + rr) * K + k0 + ck) = *(const uint4*)(&tile[rr][ck]);
  }
}

// qkv = x16 @ WqkvT^T (fp16 in, fp32 acc). Epilogue scatters per-head:
//   cols [0,768):     q16 [bh][t][64], PRE-SCALED by 8*log2(e)
//   cols [768,1536):  k16 [bh][t][64]
//   cols [1536,2304): vT  [bh][64][2048] (pre-transposed)
__global__ __launch_bounds__(256) void gemm1_qkv(const f16* __restrict__ A,
                                                 const f16* __restrict__ Bt,
                                                 f16* __restrict__ q16, f16* __restrict__ k16,
                                                 f16* __restrict__ vt) {
  __shared__ f16 As[128 * LDT];
  __shared__ f16 Bs[128 * LDT];
  int tid = threadIdx.x;
  int lane = tid & 63, wid = tid >> 6;
  int quad = lane >> 4, l16 = lane & 15;
  int wy = wid >> 1, wx = wid & 1;
  int m0 = blockIdx.x * 128, n0 = blockIdx.y * 128;
  int srow = tid >> 3, scol = (tid & 7) * 8;
  floatx4 acc[4][4] = {};
  for (int k0 = 0; k0 < 768; k0 += 64) {
    for (int p = 0; p < 4; ++p) {
      int r = srow + p * 32;
      *(uint4*)(As + r * LDT + scol) = *(const uint4*)(A + (size_t)(m0 + r) * 768 + k0 + scol);
      *(uint4*)(Bs + r * LDT + scol) = *(const uint4*)(Bt + (size_t)(n0 + r) * 768 + k0 + scol);
    }
    __syncthreads();
    for (int kk = 0; kk < 64; kk += 32) {
      f16x8 af[4], bfr[4];
      for (int i = 0; i < 4; ++i)
        af[i] = *(const f16x8*)(As + (wy * 64 + i * 16 + l16) * LDT + kk + quad * 8);
      for (int j = 0; j < 4; ++j)
        bfr[j] = *(const f16x8*)(Bs + (wx * 64 + j * 16 + l16) * LDT + kk + quad * 8);
      for (int i = 0; i < 4; ++i)
        for (int j = 0; j < 4; ++j)
          acc[i][j] = __builtin_amdgcn_mfma_f32_16x16x32_f16(af[i], bfr[j], acc[i][j], 0, 0, 0);
    }
    __syncthreads();
  }
  for (int i = 0; i < 4; ++i)
    for (int j = 0; j < 4; ++j)
      for (int r = 0; r < 4; ++r) {
        int row = m0 + wy * 64 + i * 16 + quad * 4 + r;
        int col = n0 + wx * 64 + j * 16 + l16;
        float a = acc[i][j][r];
        int b = row >> 11, t = row & 2047;
        if (col < 768) {
          int h = col >> 6, d = col & 63;
          q16[((size_t)(b * 12 + h)) * 131072 + (size_t)t * 64 + d] = (f16)(a * QSCALE);
        } else if (col < 1536) {
          int c = col - 768;
          int h = c >> 6, d = c & 63;
          k16[((size_t)(b * 12 + h)) * 131072 + (size_t)t * 64 + d] = (f16)a;
        } else {
          int c = col - 1536;
          int h = c >> 6, d = c & 63;
          vt[((size_t)(b * 12 + h)) * 131072 + (size_t)d * 2048 + t] = (f16)a;
        }
      }
}

// C[M,N](fp32) = A[M,K](f16) * Bt[N,K]^T(f16)
__global__ __launch_bounds__(256) void gemm_bt_f16(const f16* __restrict__ A,
                                                   const f16* __restrict__ Bt,
                                                   float* __restrict__ C,
                                                   int M, int N, int K) {
  __shared__ f16 As[128 * LDT];
  __shared__ f16 Bs[128 * LDT];
  int tid = threadIdx.x;
  int lane = tid & 63, wid = tid >> 6;
  int quad = lane >> 4, l16 = lane & 15;
  int wy = wid >> 1, wx = wid & 1;
  int m0 = blockIdx.x * 128, n0 = blockIdx.y * 128;
  int srow = tid >> 3, scol = (tid & 7) * 8;
  floatx4 acc[4][4] = {};
  for (int k0 = 0; k0 < K; k0 += 64) {
    for (int p = 0; p < 4; ++p) {
      int r = srow + p * 32;
      *(uint4*)(As + r * LDT + scol) = *(const uint4*)(A + (size_t)(m0 + r) * K + k0 + scol);
      *(uint4*)(Bs + r * LDT + scol) = *(const uint4*)(Bt + (size_t)(n0 + r) * K + k0 + scol);
    }
    __syncthreads();
    for (int kk = 0; kk < 64; kk += 32) {
      f16x8 af[4], bfr[4];
      for (int i = 0; i < 4; ++i)
        af[i] = *(const f16x8*)(As + (wy * 64 + i * 16 + l16) * LDT + kk + quad * 8);
      for (int j = 0; j < 4; ++j)
        bfr[j] = *(const f16x8*)(Bs + (wx * 64 + j * 16 + l16) * LDT + kk + quad * 8);
      for (int i = 0; i < 4; ++i)
        for (int j = 0; j < 4; ++j)
          acc[i][j] = __builtin_amdgcn_mfma_f32_16x16x32_f16(af[i], bfr[j], acc[i][j], 0, 0, 0);
    }
    __syncthreads();
  }
  for (int i = 0; i < 4; ++i) {
    int row = m0 + wy * 64 + i * 16 + quad * 4;
    for (int j = 0; j < 4; ++j) {
      int col = n0 + wx * 64 + j * 16 + l16;
      for (int r = 0; r < 4; ++r)
        C[(size_t)(row + r) * N + col] = acc[i][j][r];
    }
  }
}

// Flash attention v6: S^T orientation, 128-wide s-tile, single-buffered LDS.
// Per-iteration fixed softmax costs (o-rescale, alpha, shfl, l-update) amortize
// over 2x scores vs v5. LDS = Ks[128x72]+Vt[64x136] = 35.8 KB -> 4 blocks/CU.
__global__ __launch_bounds__(256, 2) void flash_attn(const f16* __restrict__ q16,
                                                     const f16* __restrict__ k16,
                                                     const f16* __restrict__ vT,
                                                     f16* __restrict__ y) {
  __shared__ f16 Ks[128 * LDT];   // [s][d]
  __shared__ f16 Vt[64 * LDTV];   // [d][s]
  const int T = 2048;
  // XCD-locality remap: all 32 q-tiles of a head land on one XCD's L2
  int xcd = blockIdx.x & 7, yb = blockIdx.x >> 3;
  int bh = xcd * 6 + (yb >> 5);
  int qt = yb & 31;
  int b = bh / 12, h = bh - b * 12;
  int tid = threadIdx.x;
  int lane = tid & 63, wid = tid >> 6;
  int quad = lane >> 4, l16 = lane & 15;
  int rk = tid >> 3, ck = (tid & 7) * 8;    // K staging: 32 rows x 64 cols per pass
  int rv = tid >> 4, cv = (tid & 15) * 8;   // V staging: 16 rows x 128 cols per pass
  size_t hb = (size_t)bh * T * 64;

  f16x8 qf[2];  // B-operand: col m = l16 -> Q row (qt*64 + wid*16 + l16)
  {
    size_t qrow = hb + (size_t)(qt * 64 + wid * 16 + l16) * 64 + quad * 8;
    qf[0] = *(const f16x8*)(q16 + qrow);
    qf[1] = *(const f16x8*)(q16 + qrow + 32);
  }
  f16x4 ones4;
  for (int e = 0; e < 4; ++e) ones4[e] = (f16)1.0f;

  float m_i = -1e30f, l_i = 0.f;
  floatx4 o[4] = {};  // O^T: dn = i*16 + quad*4 + reg, m = l16

  for (int kt = 0; kt < 16; ++kt) {
    if (kt) __syncthreads();  // prior iteration's LDS reads complete
    for (int p = 0; p < 4; ++p) {
      int r = rk + p * 32;
      *(uint4*)(Ks + r * LDT + ck) =
          *(const uint4*)(k16 + hb + (size_t)(kt * 128 + r) * 64 + ck);
      int d = rv + p * 16;
      *(uint4*)(Vt + d * LDTV + cv) =
          *(const uint4*)(vT + hb + (size_t)d * T + kt * 128 + cv);
    }
    __syncthreads();

    // S^T[s][m] = (8*log2e) * k.q : A-frag = K rows (s), B-frag = Q (m)
    floatx4 sf[8];
    const floatx4 z4 = {0.f, 0.f, 0.f, 0.f};
    for (int i = 0; i < 8; ++i) sf[i] = z4;
    for (int kk = 0; kk < 2; ++kk)
      for (int i = 0; i < 8; ++i) {
        f16x8 kf = *(const f16x8*)(Ks + (i * 16 + l16) * LDT + kk * 32 + quad * 8);
        sf[i] = __builtin_amdgcn_mfma_f32_16x16x32_f16(kf, qf[kk], sf[i], 0, 0, 0);
      }

    // online softmax over s (base 2): 32 in-lane values + cross-quad butterfly
    float mx = fmaxf(fmaxf(sf[0][0], sf[0][1]), fmaxf(sf[0][2], sf[0][3]));
    for (int i = 1; i < 8; ++i)
      mx = fmaxf(mx, fmaxf(fmaxf(sf[i][0], sf[i][1]), fmaxf(sf[i][2], sf[i][3])));
    mx = fmaxf(mx, __shfl_xor(mx, 16));
    mx = fmaxf(mx, __shfl_xor(mx, 32));
    float m_new = fmaxf(m_i, mx);
    float alpha = exp2f(m_i - m_new);
    m_i = m_new;
    for (int i = 0; i < 8; ++i)
      for (int r = 0; r < 4; ++r) sf[i][r] = exp2f(sf[i][r] - m_new);
    for (int i = 0; i < 4; ++i) o[i] *= alpha;

    // pack P^T into 16x16x16 B-operands (packed cvt): k = quad*4+j == C-layout s
    f16x4 pf[8];
    for (int i = 0; i < 8; ++i) {
      union { h16x2 h; f16 f[2]; } lo, hi;
      lo.h = __builtin_amdgcn_cvt_pkrtz(sf[i][0], sf[i][1]);
      hi.h = __builtin_amdgcn_cvt_pkrtz(sf[i][2], sf[i][3]);
      pf[i][0] = lo.f[0]; pf[i][1] = lo.f[1];
      pf[i][2] = hi.f[0]; pf[i][3] = hi.f[1];
    }

    // row sums via ones-MFMA (every lane gets full sum over s)
    floatx4 rs = z4;
    for (int si = 0; si < 8; ++si)
      rs = __builtin_amdgcn_mfma_f32_16x16x16f16(ones4, pf[si], rs, 0, 0, 0);
    l_i = l_i * alpha + rs[0];

    // O^T += V^T . P^T : A-frag = Vt rows (dn), B-frag = pf
    for (int i = 0; i < 4; ++i)
      for (int si = 0; si < 8; ++si) {
        f16x4 vf = *(const f16x4*)(Vt + (i * 16 + l16) * LDTV + si * 16 + quad * 4);
        o[i] = __builtin_amdgcn_mfma_f32_16x16x16f16(vf, pf[si], o[i], 0, 0, 0);
      }
  }

  // epilogue: O^T[dn][m] -> y[b, t=qt*64+wid*16+l16, h*64+dn]
  float invl = 1.0f / l_i;
  int t = qt * 64 + wid * 16 + l16;
  size_t off = ((size_t)(b * T + t)) * 768 + h * 64;
  for (int i = 0; i < 4; ++i)
    for (int r = 0; r < 4; ++r)
      y[off + i * 16 + quad * 4 + r] = (f16)(o[i][r] * invl);
}

extern "C" void kernel_launch(void* const* d_in, const int* in_sizes, int n_in,
                              void* d_out, int out_size, void* d_ws, size_t ws_size,
                              hipStream_t stream) {
  const float* x     = (const float*)d_in[0];  // [4,2048,768] fp32
  const float* Wqkv  = (const float*)d_in[1];  // [768,2304] fp32
  const float* Wproj = (const float*)d_in[2];  // [768,768] fp32
  float* out = (float*)d_out;                  // [4,2048,768] fp32
  char* ws = (char*)d_ws;
  f16* x16    = (f16*)ws;                  // 8192*768*2 = 12,582,912 B each
  f16* q16    = (f16*)(ws + 12582912);
  f16* k16    = (f16*)(ws + 25165824);
  f16* vT16   = (f16*)(ws + 37748736);
  f16* y16    = (f16*)(ws + 50331648);
  f16* WqkvT  = (f16*)(ws + 62914560);     // 2304*768*2 = 3,538,944 B
  f16* WprojT = (f16*)(ws + 66453504);     //  768*768*2 = 1,179,648 B
                                           // total 67,633,152 B

  convert_f32_f16<<<6144, 256, 0, stream>>>(x, x16, 6291456);
  transpose_f32_f16_tiled<<<dim3(12, 36), 256, 0, stream>>>(Wqkv, WqkvT, 768, 2304);
  transpose_f32_f16_tiled<<<dim3(12, 12), 256, 0, stream>>>(Wproj, WprojT, 768, 768);
  gemm1_qkv<<<dim3(64, 18), 256, 0, stream>>>(x16, WqkvT, q16, k16, vT16);
  flash_attn<<<1536, 256, 0, stream>>>(q16, k16, vT16, y16);
  gemm_bt_f16<<<dim3(64, 6), 256, 0, stream>>>(y16, WprojT, out, 8192, 768, 768);
}